// Round 2
// baseline (388.326 us; speedup 1.0000x reference)
//
#include <hip/hip_runtime.h>
#include <hip/hip_bf16.h>
#include <stdint.h>

#define P_B 4096
#define P_N 16384
#define P_F 768
#define P_E 512

typedef __attribute__((ext_vector_type(8))) __bf16 bf16x8;
typedef __attribute__((ext_vector_type(4))) float f32x4;

__device__ __forceinline__ unsigned short bfbits(float x) {
    __bf16 h = (__bf16)x;
    union { __bf16 h; unsigned short u; } cv;
    cv.h = h;
    return cv.u;
}
__device__ __forceinline__ float bf2f(unsigned short u) {
    union { float f; unsigned int i; } cv;
    cv.i = ((unsigned int)u) << 16;
    return cv.f;
}

// ---------------------------------------------------------------------------
// Embed: C[row][col] = src[row]·g_w[col] + g_b[col], stored bf16.
// Combined rows: 0..4095 from X, 4096..20479 from D. Also accumulates
// per-row sum of squares (of the bf16-rounded values) into norm2[].
// (unchanged from round 1)
// ---------------------------------------------------------------------------
__global__ __launch_bounds__(256, 2) void embed_kernel(
    const float* __restrict__ X, const float* __restrict__ D,
    const float* __restrict__ gw, const float* __restrict__ gb,
    unsigned short* __restrict__ emb, float* __restrict__ norm2)
{
    __shared__ unsigned short As[128 * 32];
    __shared__ unsigned short Bs[128 * 32];
    const int tid = threadIdx.x;
    const int lane = tid & 63;
    const int wave = tid >> 6;
    const int q = lane >> 4, c = lane & 15;
    const int wrow = (wave >> 1) * 64;
    const int wcol = (wave & 1) * 64;
    const int colTile = blockIdx.x;   // 0..3   (E tiles)
    const int rowTile = blockIdx.y;   // 0..159 (combined row tiles)

    const float* srcA;
    int srcRow0;
    if (rowTile < 32) { srcA = X; srcRow0 = rowTile * 128; }
    else              { srcA = D; srcRow0 = (rowTile - 32) * 128; }
    const int rowG0 = rowTile * 128;
    const int col0 = colTile * 128;

    f32x4 acc[4][4];
    const f32x4 zero = {0.f, 0.f, 0.f, 0.f};
#pragma unroll
    for (int i = 0; i < 4; i++)
#pragma unroll
        for (int j = 0; j < 4; j++) acc[i][j] = zero;

    for (int kt = 0; kt < P_F / 32; ++kt) {
        const int k0 = kt * 32;
        __syncthreads();
#pragma unroll
        for (int l = 0; l < 4; l++) {
            const int idx = l * 256 + tid;     // 0..1023
            const int row = idx >> 3;          // 0..127
            const int ch = idx & 7;            // 4-float chunk
            const float4 va = *(const float4*)(srcA + (size_t)(srcRow0 + row) * P_F + k0 + ch * 4);
            ushort4 ha;
            ha.x = bfbits(va.x); ha.y = bfbits(va.y); ha.z = bfbits(va.z); ha.w = bfbits(va.w);
            *(ushort4*)(&As[row * 32 + ch * 4]) = ha;
            const float4 vb = *(const float4*)(gw + (size_t)(col0 + row) * P_F + k0 + ch * 4);
            ushort4 hb;
            hb.x = bfbits(vb.x); hb.y = bfbits(vb.y); hb.z = bfbits(vb.z); hb.w = bfbits(vb.w);
            *(ushort4*)(&Bs[row * 32 + ch * 4]) = hb;
        }
        __syncthreads();
        bf16x8 af[4], bfr[4];
#pragma unroll
        for (int i = 0; i < 4; i++)
            af[i] = *(const bf16x8*)(&As[(wrow + i * 16 + c) * 32 + q * 8]);
#pragma unroll
        for (int j = 0; j < 4; j++)
            bfr[j] = *(const bf16x8*)(&Bs[(wcol + j * 16 + c) * 32 + q * 8]);
#pragma unroll
        for (int i = 0; i < 4; i++)
#pragma unroll
            for (int j = 0; j < 4; j++)
                acc[i][j] = __builtin_amdgcn_mfma_f32_16x16x32_bf16(af[i], bfr[j], acc[i][j], 0, 0, 0);
    }

    // epilogue: bias add, bf16 store, row-wise sum of squares
    float ss[4][4];
#pragma unroll
    for (int i = 0; i < 4; i++)
#pragma unroll
        for (int r = 0; r < 4; r++) ss[i][r] = 0.f;
#pragma unroll
    for (int j = 0; j < 4; j++) {
        const int colg = col0 + wcol + j * 16 + c;
        const float bias = gb[colg];
#pragma unroll
        for (int i = 0; i < 4; i++) {
#pragma unroll
            for (int r = 0; r < 4; r++) {
                const int rowg = rowG0 + wrow + i * 16 + q * 4 + r;
                const float v = acc[i][j][r] + bias;
                const unsigned short hb = bfbits(v);
                emb[(size_t)rowg * P_E + colg] = hb;
                const float vs = bf2f(hb);
                ss[i][r] = fmaf(vs, vs, ss[i][r]);
            }
        }
    }
#pragma unroll
    for (int i = 0; i < 4; i++)
#pragma unroll
        for (int r = 0; r < 4; r++) {
            float s = ss[i][r];
            s += __shfl_xor(s, 1);
            s += __shfl_xor(s, 2);
            s += __shfl_xor(s, 4);
            s += __shfl_xor(s, 8);
            ss[i][r] = s;
        }
    if (c == 0) {
#pragma unroll
        for (int i = 0; i < 4; i++)
#pragma unroll
            for (int r = 0; r < 4; r++) {
                const int rowg = rowG0 + wrow + i * 16 + q * 4 + r;
                atomicAdd(&norm2[rowg], ss[i][r]);
            }
    }
}

// ---------------------------------------------------------------------------
// Finalize: norm2[i] -> inv_norm^3 (X rows), inv_norm^3 * (2r-1) (D rows)
// ---------------------------------------------------------------------------
__global__ void finalize_kernel(float* __restrict__ nf, const float* __restrict__ r)
{
    const int i = blockIdx.x * 256 + threadIdx.x;
    if (i >= P_B + P_N) return;
    float nrm = sqrtf(nf[i]);
    nrm = fmaxf(nrm, 1e-12f);
    const float inv = 1.0f / nrm;
    float w = inv * inv * inv;
    if (i >= P_B) {
        const float rv = r[i - P_B];
        w *= (2.0f * rv - 1.0f);
    }
    nf[i] = w;
}

// ---------------------------------------------------------------------------
// Echo v2: NO LDS, NO barriers. Each lane's MFMA fragment is a contiguous
// 16B chunk of the row-major bf16 embedding, so we global_load_dwordx4
// fragments directly into VGPRs. Register double-buffer prefetch; the
// K-loop is fully unrolled so all loads use base+immediate offsets
// (kt*64B <= 960 < 4096). Compiler inserts fine-grained vmcnt — no
// vmcnt(0) barrier drain anywhere (the AITER pattern).
// Grid: x = btile (fast) so the whole 4MB A stays L2-resident and 32
// consecutive blocks share one B-tile.
// ---------------------------------------------------------------------------
__global__ __launch_bounds__(256, 2) void echo_kernel(
    const unsigned short* __restrict__ emb, const float* __restrict__ fbuf,
    float* __restrict__ echo)
{
    const int tid = threadIdx.x;
    const int lane = tid & 63;
    const int wave = tid >> 6;
    const int q = lane >> 4, c = lane & 15;
    const int wrow = (wave >> 1) * 64;
    const int wcol = (wave & 1) * 64;
    const int btile = blockIdx.x;  // 0..31  (fast — shares B-tile across blocks)
    const int ntile = blockIdx.y;  // 0..127
    const unsigned short* Ag = emb;                        // Xe rows
    const unsigned short* Bg = emb + (size_t)P_B * P_E;    // De rows
    const int row0 = btile * 128;
    const int col0 = ntile * 128;

    // per-lane fragment base pointers: lane (c,q) of wave reads
    // row-major [row][k] 16B chunks at row = base + i*16 + c, k = kt*32 + q*8
    const unsigned short* pa[4];
    const unsigned short* pb[4];
#pragma unroll
    for (int i = 0; i < 4; i++)
        pa[i] = Ag + (size_t)(row0 + wrow + i * 16 + c) * P_E + q * 8;
#pragma unroll
    for (int j = 0; j < 4; j++)
        pb[j] = Bg + (size_t)(col0 + wcol + j * 16 + c) * P_E + q * 8;

    f32x4 acc[4][4];
    const f32x4 zero = {0.f, 0.f, 0.f, 0.f};
#pragma unroll
    for (int i = 0; i < 4; i++)
#pragma unroll
        for (int j = 0; j < 4; j++) acc[i][j] = zero;

    bf16x8 a[2][4], b[2][4];
#pragma unroll
    for (int i = 0; i < 4; i++) {
        a[0][i] = *(const bf16x8*)(pa[i]);
        b[0][i] = *(const bf16x8*)(pb[i]);
    }

#pragma unroll
    for (int kt = 0; kt < P_E / 32; ++kt) {
        const int cur = kt & 1, nxt = cur ^ 1;
        if (kt < P_E / 32 - 1) {
#pragma unroll
            for (int i = 0; i < 4; i++) {
                a[nxt][i] = *(const bf16x8*)(pa[i] + (kt + 1) * 32);
                b[nxt][i] = *(const bf16x8*)(pb[i] + (kt + 1) * 32);
            }
        }
#pragma unroll
        for (int i = 0; i < 4; i++)
#pragma unroll
            for (int j = 0; j < 4; j++)
                acc[i][j] = __builtin_amdgcn_mfma_f32_16x16x32_bf16(a[cur][i], b[cur][j], acc[i][j], 0, 0, 0);
    }

    // epilogue: cube, weight by (ind^3*r2), reduce over columns, atomicAdd rows
    const float* fX = fbuf;
    const float* fD = fbuf + P_B;
    float wc[4];
#pragma unroll
    for (int j = 0; j < 4; j++) wc[j] = fD[col0 + wcol + j * 16 + c];
    float p[4][4];
#pragma unroll
    for (int i = 0; i < 4; i++)
#pragma unroll
        for (int r = 0; r < 4; r++) p[i][r] = 0.f;
#pragma unroll
    for (int i = 0; i < 4; i++)
#pragma unroll
        for (int j = 0; j < 4; j++)
#pragma unroll
            for (int r = 0; r < 4; r++) {
                const float v = acc[i][j][r];
                const float v3 = v * v * v;
                p[i][r] = fmaf(v3, wc[j], p[i][r]);
            }
#pragma unroll
    for (int i = 0; i < 4; i++)
#pragma unroll
        for (int r = 0; r < 4; r++) {
            float s = p[i][r];
            s += __shfl_xor(s, 1);
            s += __shfl_xor(s, 2);
            s += __shfl_xor(s, 4);
            s += __shfl_xor(s, 8);
            p[i][r] = s;
        }
    if (c == 0) {
#pragma unroll
        for (int i = 0; i < 4; i++)
#pragma unroll
            for (int r = 0; r < 4; r++) {
                const int rowg = row0 + wrow + i * 16 + q * 4 + r;
                atomicAdd(&echo[rowg], p[i][r] * fX[rowg]);
            }
    }
}

// ---------------------------------------------------------------------------
// Head: logits = echo*h_w + h_b ; preds = sigmoid(logits)
// ---------------------------------------------------------------------------
__global__ void head_kernel(const float* __restrict__ echo, const float* __restrict__ hw,
                            const float* __restrict__ hb, float* __restrict__ out)
{
    const int i = blockIdx.x * 256 + threadIdx.x;
    if (i >= P_B) return;
    const float logit = fmaf(echo[i], hw[0], hb[0]);
    out[i] = logit;
    out[P_B + i] = 1.0f / (1.0f + expf(-logit));
}

extern "C" void kernel_launch(void* const* d_in, const int* in_sizes, int n_in,
                              void* d_out, int out_size, void* d_ws, size_t ws_size,
                              hipStream_t stream)
{
    const float* X  = (const float*)d_in[0];
    const float* D  = (const float*)d_in[1];
    const float* r  = (const float*)d_in[2];
    const float* gw = (const float*)d_in[3];
    const float* gb = (const float*)d_in[4];
    const float* hw = (const float*)d_in[5];
    const float* hb = (const float*)d_in[6];
    float* out = (float*)d_out;

    char* ws = (char*)d_ws;
    // layout: emb bf16 [20480][512] | norm2/f [20480] f32 | echo [4096] f32
    unsigned short* emb = (unsigned short*)ws;
    const size_t emb_bytes = (size_t)(P_B + P_N) * P_E * sizeof(unsigned short);
    float* norm2 = (float*)(ws + emb_bytes);
    float* echo = norm2 + (P_B + P_N);

    // zero norm2 + echo (contiguous)
    hipMemsetAsync(norm2, 0, (size_t)(P_B + P_N + P_B) * sizeof(float), stream);

    embed_kernel<<<dim3(4, 160), 256, 0, stream>>>(X, D, gw, gb, emb, norm2);
    finalize_kernel<<<dim3((P_B + P_N + 255) / 256), 256, 0, stream>>>(norm2, r);
    echo_kernel<<<dim3(32, 128), 256, 0, stream>>>(emb, norm2, echo);
    head_kernel<<<dim3((P_B + 255) / 256), 256, 0, stream>>>(echo, hw, hb, out);
}

// Round 3
// 284.370 us; speedup vs baseline: 1.3656x; 1.3656x over previous
//
#include <hip/hip_runtime.h>
#include <hip/hip_bf16.h>
#include <stdint.h>

#define P_B 4096
#define P_N 16384
#define P_F 768
#define P_E 512

typedef __attribute__((ext_vector_type(8))) __bf16 bf16x8;
typedef __attribute__((ext_vector_type(4))) float f32x4;

__device__ __forceinline__ unsigned short bfbits(float x) {
    __bf16 h = (__bf16)x;
    union { __bf16 h; unsigned short u; } cv;
    cv.h = h;
    return cv.u;
}
__device__ __forceinline__ float bf2f(unsigned short u) {
    union { float f; unsigned int i; } cv;
    cv.i = ((unsigned int)u) << 16;
    return cv.f;
}

// ---------------------------------------------------------------------------
// Embed v2: C[row][col] = src[row]·g_w[col] + g_b[col], stored bf16, plus
// per-row sum-of-squares into norm2[]. Double-buffered LDS: global loads for
// kt+1 are issued into VGPRs BEFORE computing kt, converted+written to the
// other LDS buffer after compute, so vmem latency hides behind MFMA.
// ---------------------------------------------------------------------------
__global__ __launch_bounds__(256, 2) void embed_kernel(
    const float* __restrict__ X, const float* __restrict__ D,
    const float* __restrict__ gw, const float* __restrict__ gb,
    unsigned short* __restrict__ emb, float* __restrict__ norm2)
{
    __shared__ unsigned short As[2][128 * 32];
    __shared__ unsigned short Bs[2][128 * 32];
    const int tid = threadIdx.x;
    const int lane = tid & 63;
    const int wave = tid >> 6;
    const int q = lane >> 4, c = lane & 15;
    const int wrow = (wave >> 1) * 64;
    const int wcol = (wave & 1) * 64;
    const int colTile = blockIdx.x;   // 0..3   (E tiles)
    const int rowTile = blockIdx.y;   // 0..159 (combined row tiles)

    const float* srcA;
    int srcRow0;
    if (rowTile < 32) { srcA = X; srcRow0 = rowTile * 128; }
    else              { srcA = D; srcRow0 = (rowTile - 32) * 128; }
    const int rowG0 = rowTile * 128;
    const int col0 = colTile * 128;

    f32x4 acc[4][4];
    const f32x4 zero = {0.f, 0.f, 0.f, 0.f};
#pragma unroll
    for (int i = 0; i < 4; i++)
#pragma unroll
        for (int j = 0; j < 4; j++) acc[i][j] = zero;

    float4 va[4], vb[4];

    // issue global loads for tile kt into va/vb
    auto issue = [&](int kt) {
        const int k0 = kt * 32;
#pragma unroll
        for (int l = 0; l < 4; l++) {
            const int idx = l * 256 + tid;     // 0..1023
            const int row = idx >> 3;          // 0..127
            const int ch = idx & 7;            // 4-float chunk
            va[l] = *(const float4*)(srcA + (size_t)(srcRow0 + row) * P_F + k0 + ch * 4);
            vb[l] = *(const float4*)(gw + (size_t)(col0 + row) * P_F + k0 + ch * 4);
        }
    };
    // convert + write va/vb into LDS buffer `buf`
    auto commit = [&](int buf) {
#pragma unroll
        for (int l = 0; l < 4; l++) {
            const int idx = l * 256 + tid;
            const int row = idx >> 3;
            const int ch = idx & 7;
            ushort4 ha;
            ha.x = bfbits(va[l].x); ha.y = bfbits(va[l].y); ha.z = bfbits(va[l].z); ha.w = bfbits(va[l].w);
            *(ushort4*)(&As[buf][row * 32 + ch * 4]) = ha;
            ushort4 hb;
            hb.x = bfbits(vb[l].x); hb.y = bfbits(vb[l].y); hb.z = bfbits(vb[l].z); hb.w = bfbits(vb[l].w);
            *(ushort4*)(&Bs[buf][row * 32 + ch * 4]) = hb;
        }
    };

    issue(0);
    commit(0);
    __syncthreads();

    for (int kt = 0; kt < P_F / 32; ++kt) {
        const int cur = kt & 1;
        if (kt < P_F / 32 - 1) issue(kt + 1);

        bf16x8 af[4], bfr[4];
#pragma unroll
        for (int i = 0; i < 4; i++)
            af[i] = *(const bf16x8*)(&As[cur][(wrow + i * 16 + c) * 32 + q * 8]);
#pragma unroll
        for (int j = 0; j < 4; j++)
            bfr[j] = *(const bf16x8*)(&Bs[cur][(wcol + j * 16 + c) * 32 + q * 8]);
#pragma unroll
        for (int i = 0; i < 4; i++)
#pragma unroll
            for (int j = 0; j < 4; j++)
                acc[i][j] = __builtin_amdgcn_mfma_f32_16x16x32_bf16(af[i], bfr[j], acc[i][j], 0, 0, 0);

        if (kt < P_F / 32 - 1) commit(cur ^ 1);
        __syncthreads();
    }

    // epilogue: bias add, bf16 store, row-wise sum of squares
    float ss[4][4];
#pragma unroll
    for (int i = 0; i < 4; i++)
#pragma unroll
        for (int r = 0; r < 4; r++) ss[i][r] = 0.f;
#pragma unroll
    for (int j = 0; j < 4; j++) {
        const int colg = col0 + wcol + j * 16 + c;
        const float bias = gb[colg];
#pragma unroll
        for (int i = 0; i < 4; i++) {
#pragma unroll
            for (int r = 0; r < 4; r++) {
                const int rowg = rowG0 + wrow + i * 16 + q * 4 + r;
                const float v = acc[i][j][r] + bias;
                const unsigned short hb = bfbits(v);
                emb[(size_t)rowg * P_E + colg] = hb;
                const float vs = bf2f(hb);
                ss[i][r] = fmaf(vs, vs, ss[i][r]);
            }
        }
    }
#pragma unroll
    for (int i = 0; i < 4; i++)
#pragma unroll
        for (int r = 0; r < 4; r++) {
            float s = ss[i][r];
            s += __shfl_xor(s, 1);
            s += __shfl_xor(s, 2);
            s += __shfl_xor(s, 4);
            s += __shfl_xor(s, 8);
            ss[i][r] = s;
        }
    if (c == 0) {
#pragma unroll
        for (int i = 0; i < 4; i++)
#pragma unroll
            for (int r = 0; r < 4; r++) {
                const int rowg = rowG0 + wrow + i * 16 + q * 4 + r;
                atomicAdd(&norm2[rowg], ss[i][r]);
            }
    }
}

// ---------------------------------------------------------------------------
// Finalize: norm2[i] -> inv_norm^3 (X rows), inv_norm^3 * (2r-1) (D rows)
// ---------------------------------------------------------------------------
__global__ void finalize_kernel(float* __restrict__ nf, const float* __restrict__ r)
{
    const int i = blockIdx.x * 256 + threadIdx.x;
    if (i >= P_B + P_N) return;
    float nrm = sqrtf(nf[i]);
    nrm = fmaxf(nrm, 1e-12f);
    const float inv = 1.0f / nrm;
    float w = inv * inv * inv;
    if (i >= P_B) {
        const float rv = r[i - P_B];
        w *= (2.0f * rv - 1.0f);
    }
    nf[i] = w;
}

// ---------------------------------------------------------------------------
// Echo v3: LDS staging (coalesced global_load_lds width=16) with DOUBLE
// buffering: loads for kt+1 are issued before computing kt, so the barrier's
// vmcnt drain waits on loads that are already ~complete. One barrier/iter.
// ---------------------------------------------------------------------------
__global__ __launch_bounds__(256, 4) void echo_kernel(
    const unsigned short* __restrict__ emb, const float* __restrict__ fbuf,
    float* __restrict__ echo)
{
    __shared__ unsigned short As[2][128 * 32];
    __shared__ unsigned short Bs[2][128 * 32];
    const int tid = threadIdx.x;
    const int lane = tid & 63;
    const int wave = tid >> 6;
    const int q = lane >> 4, c = lane & 15;
    const int wrow = (wave >> 1) * 64;
    const int wcol = (wave & 1) * 64;
    const int ntile = blockIdx.x;  // 0..127 (fast: consecutive blocks share A-tile)
    const int btile = blockIdx.y;  // 0..31
    const unsigned short* Ag = emb;                        // Xe rows
    const unsigned short* Bg = emb + (size_t)P_B * P_E;    // De rows
    const int row0 = btile * 128;
    const int col0 = ntile * 128;

    f32x4 acc[4][4];
    const f32x4 zero = {0.f, 0.f, 0.f, 0.f};
#pragma unroll
    for (int i = 0; i < 4; i++)
#pragma unroll
        for (int j = 0; j < 4; j++) acc[i][j] = zero;

    auto stage = [&](int buf, int kt) {
        const int k0 = kt * 32;
#pragma unroll
        for (int l = 0; l < 2; l++) {
            const int idx = l * 256 + tid;   // 0..511
            const int row = idx >> 2;        // 0..127
            const int ch = idx & 3;          // 16B chunk within the 64B row
            __builtin_amdgcn_global_load_lds(
                (const __attribute__((address_space(1))) unsigned int*)(Ag + (size_t)(row0 + row) * P_E + k0 + ch * 8),
                (__attribute__((address_space(3))) unsigned int*)(&As[buf][l * 2048 + wave * 512]),
                16, 0, 0);
            __builtin_amdgcn_global_load_lds(
                (const __attribute__((address_space(1))) unsigned int*)(Bg + (size_t)(col0 + row) * P_E + k0 + ch * 8),
                (__attribute__((address_space(3))) unsigned int*)(&Bs[buf][l * 2048 + wave * 512]),
                16, 0, 0);
        }
    };

    stage(0, 0);
    __syncthreads();

    for (int kt = 0; kt < P_E / 32; ++kt) {
        const int cur = kt & 1;
        if (kt < P_E / 32 - 1) stage(cur ^ 1, kt + 1);

        bf16x8 af[4], bfr[4];
#pragma unroll
        for (int i = 0; i < 4; i++)
            af[i] = *(const bf16x8*)(&As[cur][(wrow + i * 16 + c) * 32 + q * 8]);
#pragma unroll
        for (int j = 0; j < 4; j++)
            bfr[j] = *(const bf16x8*)(&Bs[cur][(wcol + j * 16 + c) * 32 + q * 8]);
#pragma unroll
        for (int i = 0; i < 4; i++)
#pragma unroll
            for (int j = 0; j < 4; j++)
                acc[i][j] = __builtin_amdgcn_mfma_f32_16x16x32_bf16(af[i], bfr[j], acc[i][j], 0, 0, 0);

        __syncthreads();
    }

    // epilogue: cube, weight by (ind^3*r2), reduce over columns, atomicAdd rows
    const float* fX = fbuf;
    const float* fD = fbuf + P_B;
    float wc[4];
#pragma unroll
    for (int j = 0; j < 4; j++) wc[j] = fD[col0 + wcol + j * 16 + c];
    float p[4][4];
#pragma unroll
    for (int i = 0; i < 4; i++)
#pragma unroll
        for (int r = 0; r < 4; r++) p[i][r] = 0.f;
#pragma unroll
    for (int i = 0; i < 4; i++)
#pragma unroll
        for (int j = 0; j < 4; j++)
#pragma unroll
            for (int r = 0; r < 4; r++) {
                const float v = acc[i][j][r];
                const float v3 = v * v * v;
                p[i][r] = fmaf(v3, wc[j], p[i][r]);
            }
#pragma unroll
    for (int i = 0; i < 4; i++)
#pragma unroll
        for (int r = 0; r < 4; r++) {
            float s = p[i][r];
            s += __shfl_xor(s, 1);
            s += __shfl_xor(s, 2);
            s += __shfl_xor(s, 4);
            s += __shfl_xor(s, 8);
            p[i][r] = s;
        }
    if (c == 0) {
#pragma unroll
        for (int i = 0; i < 4; i++)
#pragma unroll
            for (int r = 0; r < 4; r++) {
                const int rowg = row0 + wrow + i * 16 + q * 4 + r;
                atomicAdd(&echo[rowg], p[i][r] * fX[rowg]);
            }
    }
}

// ---------------------------------------------------------------------------
// Head: logits = echo*h_w + h_b ; preds = sigmoid(logits)
// ---------------------------------------------------------------------------
__global__ void head_kernel(const float* __restrict__ echo, const float* __restrict__ hw,
                            const float* __restrict__ hb, float* __restrict__ out)
{
    const int i = blockIdx.x * 256 + threadIdx.x;
    if (i >= P_B) return;
    const float logit = fmaf(echo[i], hw[0], hb[0]);
    out[i] = logit;
    out[P_B + i] = 1.0f / (1.0f + expf(-logit));
}

extern "C" void kernel_launch(void* const* d_in, const int* in_sizes, int n_in,
                              void* d_out, int out_size, void* d_ws, size_t ws_size,
                              hipStream_t stream)
{
    const float* X  = (const float*)d_in[0];
    const float* D  = (const float*)d_in[1];
    const float* r  = (const float*)d_in[2];
    const float* gw = (const float*)d_in[3];
    const float* gb = (const float*)d_in[4];
    const float* hw = (const float*)d_in[5];
    const float* hb = (const float*)d_in[6];
    float* out = (float*)d_out;

    char* ws = (char*)d_ws;
    // layout: emb bf16 [20480][512] | norm2/f [20480] f32 | echo [4096] f32
    unsigned short* emb = (unsigned short*)ws;
    const size_t emb_bytes = (size_t)(P_B + P_N) * P_E * sizeof(unsigned short);
    float* norm2 = (float*)(ws + emb_bytes);
    float* echo = norm2 + (P_B + P_N);

    // zero norm2 + echo (contiguous)
    hipMemsetAsync(norm2, 0, (size_t)(P_B + P_N + P_B) * sizeof(float), stream);

    embed_kernel<<<dim3(4, 160), 256, 0, stream>>>(X, D, gw, gb, emb, norm2);
    finalize_kernel<<<dim3((P_B + P_N + 255) / 256), 256, 0, stream>>>(norm2, r);
    echo_kernel<<<dim3(128, 32), 256, 0, stream>>>(emb, norm2, echo);
    head_kernel<<<dim3((P_B + 255) / 256), 256, 0, stream>>>(echo, hw, hb, out);
}

// Round 4
// 227.873 us; speedup vs baseline: 1.7041x; 1.2479x over previous
//
#include <hip/hip_runtime.h>
#include <hip/hip_bf16.h>
#include <stdint.h>

#define P_B 4096
#define P_N 16384
#define P_F 768
#define P_E 512
#define NKT_F 24   // 768/32 k-tiles
#define NKT_E 16   // 512/32 k-tiles

typedef __attribute__((ext_vector_type(8))) __bf16 bf16x8;
typedef __attribute__((ext_vector_type(8))) unsigned short u16x8;
typedef __attribute__((ext_vector_type(4))) float f32x4;

__device__ __forceinline__ unsigned short bfbits(float x) {
    __bf16 h = (__bf16)x;
    union { __bf16 h; unsigned short u; } cv;
    cv.h = h;
    return cv.u;
}
__device__ __forceinline__ float bf2f(unsigned short u) {
    union { float f; unsigned int i; } cv;
    cv.i = ((unsigned int)u) << 16;
    return cv.f;
}

// Fragment-packed layout: element (r,k) of a [R][K] bf16 matrix lives at
//   (((r>>4)*NKT + (k>>5))*64 + ((k>>3)&3)*16 + (r&15))*8 + (k&7)
// so one wave's MFMA fragment for (row-block rb, k-tile kt) is the 1KB run
// [base + lane*16B], lane = q*16+c  ->  perfectly coalesced, no LDS needed.
__device__ __forceinline__ size_t pk16(int r, int k) {
    return ((size_t)((r >> 4) * NKT_E + (k >> 5)) * 64 + ((k >> 3) & 3) * 16 + (r & 15)) * 8 + (k & 7);
}

// ---------------------------------------------------------------------------
// Convert+pack: X/D/gw fp32 row-major -> bf16 fragment-packed.
// xdpk rows 0..4095 = X, 4096..20479 = D (1280 row-blocks); gwpk 512 rows.
// One wave per (rb, kt): reads 16 rows x 128B (full lines), writes 1KB coalesced.
// ---------------------------------------------------------------------------
__global__ __launch_bounds__(256) void convert_pack_kernel(
    const float* __restrict__ X, const float* __restrict__ D,
    const float* __restrict__ gw,
    unsigned short* __restrict__ xdpk, unsigned short* __restrict__ gwpk)
{
    const int wave = threadIdx.x >> 6, lane = threadIdx.x & 63;
    const int task = blockIdx.x * 4 + wave;      // 0..31487
    const int rb = task / NKT_F;                 // 0..1311
    const int kt = task - rb * NKT_F;            // 0..23
    const int c16 = lane & 15, q = lane >> 4;
    const float* src;
    unsigned short* dst;
    if (rb < 256) {
        src = X + (size_t)(rb * 16 + c16) * P_F;
        dst = xdpk + ((size_t)(rb * NKT_F + kt) * 64 + lane) * 8;
    } else if (rb < 1280) {
        src = D + (size_t)((rb - 256) * 16 + c16) * P_F;
        dst = xdpk + ((size_t)(rb * NKT_F + kt) * 64 + lane) * 8;
    } else {
        src = gw + (size_t)((rb - 1280) * 16 + c16) * P_F;
        dst = gwpk + ((size_t)((rb - 1280) * NKT_F + kt) * 64 + lane) * 8;
    }
    const int k0 = kt * 32 + q * 8;
    const float4 f0 = *(const float4*)(src + k0);
    const float4 f1 = *(const float4*)(src + k0 + 4);
    u16x8 h;
    h[0] = bfbits(f0.x); h[1] = bfbits(f0.y); h[2] = bfbits(f0.z); h[3] = bfbits(f0.w);
    h[4] = bfbits(f1.x); h[5] = bfbits(f1.y); h[6] = bfbits(f1.z); h[7] = bfbits(f1.w);
    *(u16x8*)dst = h;
}

// ---------------------------------------------------------------------------
// Embed (packed path): emb[row][col] = xd[row]·gw[col] + gb[col].
// Barrier-free: fragment loads straight from packed global. Epilogue stores
// the embedding in packed layout (for echo) + per-row sum-of-squares.
// ---------------------------------------------------------------------------
__global__ __launch_bounds__(256, 2) void embed_pk_kernel(
    const unsigned short* __restrict__ xdpk, const unsigned short* __restrict__ gwpk,
    const float* __restrict__ gb,
    unsigned short* __restrict__ embpk, float* __restrict__ norm2)
{
    const int tid = threadIdx.x, lane = tid & 63, wave = tid >> 6;
    const int q = lane >> 4, c = lane & 15;
    const int colTile = blockIdx.x;   // 0..3
    const int rowTile = blockIdx.y;   // 0..159
    const int rbA0 = rowTile * 8 + (wave >> 1) * 4;
    const int rbB0 = colTile * 8 + (wave & 1) * 4;

    const unsigned short* pa[4];
    const unsigned short* pb[4];
#pragma unroll
    for (int i = 0; i < 4; i++)
        pa[i] = xdpk + ((size_t)(rbA0 + i) * NKT_F * 64 + lane) * 8;
#pragma unroll
    for (int j = 0; j < 4; j++)
        pb[j] = gwpk + ((size_t)(rbB0 + j) * NKT_F * 64 + lane) * 8;

    f32x4 acc[4][4];
    const f32x4 zero = {0.f, 0.f, 0.f, 0.f};
#pragma unroll
    for (int i = 0; i < 4; i++)
#pragma unroll
        for (int j = 0; j < 4; j++) acc[i][j] = zero;

#pragma unroll
    for (int kt = 0; kt < NKT_F; ++kt) {
        bf16x8 af[4], bfr[4];
#pragma unroll
        for (int i = 0; i < 4; i++) af[i] = *(const bf16x8*)(pa[i] + (size_t)kt * 512);
#pragma unroll
        for (int j = 0; j < 4; j++) bfr[j] = *(const bf16x8*)(pb[j] + (size_t)kt * 512);
#pragma unroll
        for (int i = 0; i < 4; i++)
#pragma unroll
            for (int j = 0; j < 4; j++)
                acc[i][j] = __builtin_amdgcn_mfma_f32_16x16x32_bf16(af[i], bfr[j], acc[i][j], 0, 0, 0);
    }

    // epilogue: bias, packed bf16 store, row-wise sum of squares
    float ss[4][4];
#pragma unroll
    for (int i = 0; i < 4; i++)
#pragma unroll
        for (int r = 0; r < 4; r++) ss[i][r] = 0.f;
#pragma unroll
    for (int j = 0; j < 4; j++) {
        const int colg = colTile * 128 + (wave & 1) * 64 + j * 16 + c;
        const float bias = gb[colg];
#pragma unroll
        for (int i = 0; i < 4; i++) {
#pragma unroll
            for (int r = 0; r < 4; r++) {
                const int rowg = rowTile * 128 + (wave >> 1) * 64 + i * 16 + q * 4 + r;
                const float v = acc[i][j][r] + bias;
                const unsigned short hb = bfbits(v);
                embpk[pk16(rowg, colg)] = hb;
                const float vs = bf2f(hb);
                ss[i][r] = fmaf(vs, vs, ss[i][r]);
            }
        }
    }
#pragma unroll
    for (int i = 0; i < 4; i++)
#pragma unroll
        for (int r = 0; r < 4; r++) {
            float s = ss[i][r];
            s += __shfl_xor(s, 1);
            s += __shfl_xor(s, 2);
            s += __shfl_xor(s, 4);
            s += __shfl_xor(s, 8);
            ss[i][r] = s;
        }
    if (c == 0) {
#pragma unroll
        for (int i = 0; i < 4; i++)
#pragma unroll
            for (int r = 0; r < 4; r++) {
                const int rowg = rowTile * 128 + (wave >> 1) * 64 + i * 16 + q * 4 + r;
                atomicAdd(&norm2[rowg], ss[i][r]);
            }
    }
}

// ---------------------------------------------------------------------------
// Embed (fallback, small-ws path): r1-style LDS kernel reading raw fp32,
// storing packed. Known-good structure.
// ---------------------------------------------------------------------------
__global__ __launch_bounds__(256, 2) void embed_lds_kernel(
    const float* __restrict__ X, const float* __restrict__ D,
    const float* __restrict__ gw, const float* __restrict__ gb,
    unsigned short* __restrict__ embpk, float* __restrict__ norm2)
{
    __shared__ unsigned short As[128 * 32];
    __shared__ unsigned short Bs[128 * 32];
    const int tid = threadIdx.x;
    const int lane = tid & 63;
    const int wave = tid >> 6;
    const int q = lane >> 4, c = lane & 15;
    const int wrow = (wave >> 1) * 64;
    const int wcol = (wave & 1) * 64;
    const int colTile = blockIdx.x;
    const int rowTile = blockIdx.y;

    const float* srcA;
    int srcRow0;
    if (rowTile < 32) { srcA = X; srcRow0 = rowTile * 128; }
    else              { srcA = D; srcRow0 = (rowTile - 32) * 128; }
    const int rowG0 = rowTile * 128;
    const int col0 = colTile * 128;

    f32x4 acc[4][4];
    const f32x4 zero = {0.f, 0.f, 0.f, 0.f};
#pragma unroll
    for (int i = 0; i < 4; i++)
#pragma unroll
        for (int j = 0; j < 4; j++) acc[i][j] = zero;

    for (int kt = 0; kt < P_F / 32; ++kt) {
        const int k0 = kt * 32;
        __syncthreads();
#pragma unroll
        for (int l = 0; l < 4; l++) {
            const int idx = l * 256 + tid;
            const int row = idx >> 3;
            const int ch = idx & 7;
            const float4 va = *(const float4*)(srcA + (size_t)(srcRow0 + row) * P_F + k0 + ch * 4);
            ushort4 ha;
            ha.x = bfbits(va.x); ha.y = bfbits(va.y); ha.z = bfbits(va.z); ha.w = bfbits(va.w);
            *(ushort4*)(&As[row * 32 + ch * 4]) = ha;
            const float4 vb = *(const float4*)(gw + (size_t)(col0 + row) * P_F + k0 + ch * 4);
            ushort4 hb;
            hb.x = bfbits(vb.x); hb.y = bfbits(vb.y); hb.z = bfbits(vb.z); hb.w = bfbits(vb.w);
            *(ushort4*)(&Bs[row * 32 + ch * 4]) = hb;
        }
        __syncthreads();
        bf16x8 af[4], bfr[4];
#pragma unroll
        for (int i = 0; i < 4; i++)
            af[i] = *(const bf16x8*)(&As[(wrow + i * 16 + c) * 32 + q * 8]);
#pragma unroll
        for (int j = 0; j < 4; j++)
            bfr[j] = *(const bf16x8*)(&Bs[(wcol + j * 16 + c) * 32 + q * 8]);
#pragma unroll
        for (int i = 0; i < 4; i++)
#pragma unroll
            for (int j = 0; j < 4; j++)
                acc[i][j] = __builtin_amdgcn_mfma_f32_16x16x32_bf16(af[i], bfr[j], acc[i][j], 0, 0, 0);
    }

    float ss[4][4];
#pragma unroll
    for (int i = 0; i < 4; i++)
#pragma unroll
        for (int r = 0; r < 4; r++) ss[i][r] = 0.f;
#pragma unroll
    for (int j = 0; j < 4; j++) {
        const int colg = col0 + wcol + j * 16 + c;
        const float bias = gb[colg];
#pragma unroll
        for (int i = 0; i < 4; i++) {
#pragma unroll
            for (int r = 0; r < 4; r++) {
                const int rowg = rowG0 + wrow + i * 16 + q * 4 + r;
                const float v = acc[i][j][r] + bias;
                const unsigned short hb = bfbits(v);
                embpk[pk16(rowg, colg)] = hb;
                const float vs = bf2f(hb);
                ss[i][r] = fmaf(vs, vs, ss[i][r]);
            }
        }
    }
#pragma unroll
    for (int i = 0; i < 4; i++)
#pragma unroll
        for (int r = 0; r < 4; r++) {
            float s = ss[i][r];
            s += __shfl_xor(s, 1);
            s += __shfl_xor(s, 2);
            s += __shfl_xor(s, 4);
            s += __shfl_xor(s, 8);
            ss[i][r] = s;
        }
    if (c == 0) {
#pragma unroll
        for (int i = 0; i < 4; i++)
#pragma unroll
            for (int r = 0; r < 4; r++) {
                const int rowg = rowG0 + wrow + i * 16 + q * 4 + r;
                atomicAdd(&norm2[rowg], ss[i][r]);
            }
    }
}

// ---------------------------------------------------------------------------
// Finalize: norm2[i] -> inv_norm^3 (X rows), inv_norm^3 * (2r-1) (D rows)
// ---------------------------------------------------------------------------
__global__ void finalize_kernel(float* __restrict__ nf, const float* __restrict__ r)
{
    const int i = blockIdx.x * 256 + threadIdx.x;
    if (i >= P_B + P_N) return;
    float nrm = sqrtf(nf[i]);
    nrm = fmaxf(nrm, 1e-12f);
    const float inv = 1.0f / nrm;
    float w = inv * inv * inv;
    if (i >= P_B) {
        const float rv = r[i - P_B];
        w *= (2.0f * rv - 1.0f);
    }
    nf[i] = w;
}

// ---------------------------------------------------------------------------
// Echo (packed): barrier-free, LDS-free. Fully unrolled K-loop of coalesced
// 1KB fragment loads + MFMA; compiler schedules with fine-grained vmcnt.
// 8x8-supertile grid swizzle keeps the L2 working set ~2MB per 64 blocks.
// ---------------------------------------------------------------------------
__global__ __launch_bounds__(256, 2) void echo_pk_kernel(
    const unsigned short* __restrict__ embpk, const float* __restrict__ fbuf,
    float* __restrict__ echo)
{
    const int tid = threadIdx.x, lane = tid & 63, wave = tid >> 6;
    const int q = lane >> 4, c = lane & 15;
    const int bid = blockIdx.x;          // 0..4095
    const int sb = bid >> 6, w = bid & 63;
    const int btile = (sb & 3) * 8 + (w & 7);    // 0..31
    const int ntile = (sb >> 2) * 8 + (w >> 3);  // 0..127
    const int row0 = btile * 128;
    const int col0 = ntile * 128;
    const int rbA0 = btile * 8 + (wave >> 1) * 4;
    const int rbB0 = 256 + ntile * 8 + (wave & 1) * 4;   // De rows start at rb 256

    const unsigned short* pa[4];
    const unsigned short* pb[4];
#pragma unroll
    for (int i = 0; i < 4; i++)
        pa[i] = embpk + ((size_t)(rbA0 + i) * NKT_E * 64 + lane) * 8;
#pragma unroll
    for (int j = 0; j < 4; j++)
        pb[j] = embpk + ((size_t)(rbB0 + j) * NKT_E * 64 + lane) * 8;

    f32x4 acc[4][4];
    const f32x4 zero = {0.f, 0.f, 0.f, 0.f};
#pragma unroll
    for (int i = 0; i < 4; i++)
#pragma unroll
        for (int j = 0; j < 4; j++) acc[i][j] = zero;

#pragma unroll
    for (int kt = 0; kt < NKT_E; ++kt) {
        bf16x8 af[4], bfr[4];
#pragma unroll
        for (int i = 0; i < 4; i++) af[i] = *(const bf16x8*)(pa[i] + (size_t)kt * 512);
#pragma unroll
        for (int j = 0; j < 4; j++) bfr[j] = *(const bf16x8*)(pb[j] + (size_t)kt * 512);
#pragma unroll
        for (int i = 0; i < 4; i++)
#pragma unroll
            for (int j = 0; j < 4; j++)
                acc[i][j] = __builtin_amdgcn_mfma_f32_16x16x32_bf16(af[i], bfr[j], acc[i][j], 0, 0, 0);
    }

    // epilogue: cube, weight by (ind^3*r2), reduce over columns, atomicAdd rows
    const float* fX = fbuf;
    const float* fD = fbuf + P_B;
    float wc[4];
#pragma unroll
    for (int j = 0; j < 4; j++) wc[j] = fD[col0 + (wave & 1) * 64 + j * 16 + c];
    float p[4][4];
#pragma unroll
    for (int i = 0; i < 4; i++)
#pragma unroll
        for (int r = 0; r < 4; r++) p[i][r] = 0.f;
#pragma unroll
    for (int i = 0; i < 4; i++)
#pragma unroll
        for (int j = 0; j < 4; j++)
#pragma unroll
            for (int r = 0; r < 4; r++) {
                const float v = acc[i][j][r];
                const float v3 = v * v * v;
                p[i][r] = fmaf(v3, wc[j], p[i][r]);
            }
#pragma unroll
    for (int i = 0; i < 4; i++)
#pragma unroll
        for (int r = 0; r < 4; r++) {
            float s = p[i][r];
            s += __shfl_xor(s, 1);
            s += __shfl_xor(s, 2);
            s += __shfl_xor(s, 4);
            s += __shfl_xor(s, 8);
            p[i][r] = s;
        }
    if (c == 0) {
#pragma unroll
        for (int i = 0; i < 4; i++)
#pragma unroll
            for (int r = 0; r < 4; r++) {
                const int rowg = row0 + (wave >> 1) * 64 + i * 16 + q * 4 + r;
                atomicAdd(&echo[rowg], p[i][r] * fX[rowg]);
            }
    }
}

// ---------------------------------------------------------------------------
// Head: logits = echo*h_w + h_b ; preds = sigmoid(logits)
// ---------------------------------------------------------------------------
__global__ void head_kernel(const float* __restrict__ echo, const float* __restrict__ hw,
                            const float* __restrict__ hb, float* __restrict__ out)
{
    const int i = blockIdx.x * 256 + threadIdx.x;
    if (i >= P_B) return;
    const float logit = fmaf(echo[i], hw[0], hb[0]);
    out[i] = logit;
    out[P_B + i] = 1.0f / (1.0f + expf(-logit));
}

extern "C" void kernel_launch(void* const* d_in, const int* in_sizes, int n_in,
                              void* d_out, int out_size, void* d_ws, size_t ws_size,
                              hipStream_t stream)
{
    const float* X  = (const float*)d_in[0];
    const float* D  = (const float*)d_in[1];
    const float* r  = (const float*)d_in[2];
    const float* gw = (const float*)d_in[3];
    const float* gb = (const float*)d_in[4];
    const float* hw = (const float*)d_in[5];
    const float* hb = (const float*)d_in[6];
    float* out = (float*)d_out;

    char* ws = (char*)d_ws;
    const size_t xdpk_bytes  = (size_t)1280 * NKT_F * 64 * 8 * 2;   // 31,457,280
    const size_t gwpk_bytes  = (size_t)32 * NKT_F * 64 * 8 * 2;     //    786,432
    const size_t embpk_bytes = (size_t)1280 * NKT_E * 64 * 8 * 2;   // 20,971,520
    const size_t tail_bytes  = (size_t)(P_B + P_N + P_B) * sizeof(float);
    const size_t need_full = xdpk_bytes + gwpk_bytes + embpk_bytes + tail_bytes;
    const bool full = (ws_size >= need_full);

    unsigned short* xdpk = (unsigned short*)ws;
    unsigned short* gwpk = (unsigned short*)(ws + xdpk_bytes);
    unsigned short* embpk = full ? (unsigned short*)(ws + xdpk_bytes + gwpk_bytes)
                                 : (unsigned short*)ws;
    float* norm2 = (float*)((char*)embpk + embpk_bytes);
    float* echo = norm2 + (P_B + P_N);

    hipMemsetAsync(norm2, 0, tail_bytes, stream);

    if (full) {
        convert_pack_kernel<<<dim3(7872), 256, 0, stream>>>(X, D, gw, xdpk, gwpk);
        embed_pk_kernel<<<dim3(4, 160), 256, 0, stream>>>(xdpk, gwpk, gb, embpk, norm2);
    } else {
        embed_lds_kernel<<<dim3(4, 160), 256, 0, stream>>>(X, D, gw, gb, embpk, norm2);
    }
    finalize_kernel<<<dim3((P_B + P_N + 255) / 256), 256, 0, stream>>>(norm2, r);
    echo_pk_kernel<<<dim3(4096), 256, 0, stream>>>(embpk, norm2, echo);
    head_kernel<<<dim3((P_B + 255) / 256), 256, 0, stream>>>(echo, hw, hb, out);
}